// Round 9
// baseline (84.212 us; speedup 1.0000x reference)
//
#include <hip/hip_runtime.h>
#include <hip/hip_cooperative_groups.h>

namespace cg = cooperative_groups;

typedef float v2f __attribute__((ext_vector_type(2)));

#define N 512
#define P 2
#define DX 128
#define CLAMP_C 1e-4f
#define LOG2E_C 1.4426950408889634f
#define LN2_C 0.6931471805599453f
#define LOG2PI_C 1.8378770664093453f

#define NQ 8                 // j-values per tile (16 output streams)

// ws float offsets
#define WS_EDX    0          // 65536: exp(-d[i,k]), [i][k] (k=127 pad, masked)
#define WS_EU     65536      // 131072: exp(-u[jd,k]), jd=j*2+dz
#define WS_PART   196608     // 16384: [(jt*16+o)][c] log2-partials
#define WS_C0P    212992     // 128: per-block partial of sum (1-x~)*d
#define WS_T0P    213248     // 128: partial of sum (1-x~)*theta0[k+1]
#define WS_T1P    213504     // 128: partial of sum (1-x~)*theta1[k+1]
#define WS_S0     213760     // 1

#define EXP2F(v) __builtin_amdgcn_exp2f(v)

__device__ __forceinline__ v2f splat2(float a) { v2f r; r.x = a; r.y = a; return r; }

// log2(m) for m in [1,2): deg-5 Taylor @1.5, |err| <= ~4.6e-4 (budget ~1e5)
__device__ __forceinline__ float log2s(float m) {
    const float t = m - 1.5f;
    float p = t * 0.03799691f + -0.07124420f;
    p = p * t + 0.14248840f;
    p = p * t + -0.32059890f;
    p = p * t + 0.96179669f;
    p = p * t + 0.58496250f;
    return p;
}

// strip exponent into integer accumulator, renormalize mantissa to [1,2)
__device__ __forceinline__ float strip_add(float v, int& acc) {
    const unsigned b = __float_as_uint(v);
    acc += (int)(b >> 23);                         // biased; bias removed at end
    return __uint_as_float((b & 0x007fffffu) | 0x3f800000u);
}

__global__ __launch_bounds__(512)
void fused_kernel(const float* __restrict__ z, const float* __restrict__ x,
                  const float* __restrict__ theta, float* __restrict__ ws,
                  float* __restrict__ out) {
    const int tid = threadIdx.x;
    const int bid = blockIdx.x;
    const int gtid = bid * 512 + tid;

    __shared__ float rbuf[8][3];
    __shared__ float sbuf[8];
    __shared__ float red[2][4][16];
    __shared__ float fbuf[8][3];

    // ================= phase 1: tables + linear partials + S0 =================
    if (bid < 128) {                               // edx item: g = gtid < 65536
        const int g = gtid;
        const int i = g >> 7, k = g & 127;
        const float* xr = x + i * DX;
        // d[i,k] = sum_m 0.1^(m+1) x[i,k-m]; taps < 1e-7 dropped
        float d = 0.1f * xr[k];
        if (k >= 1) d = __builtin_fmaf(1e-2f, xr[k - 1], d);
        if (k >= 2) d = __builtin_fmaf(1e-3f, xr[k - 2], d);
        if (k >= 3) d = __builtin_fmaf(1e-4f, xr[k - 3], d);
        if (k >= 4) d = __builtin_fmaf(1e-5f, xr[k - 4], d);
        if (k >= 5) d = __builtin_fmaf(1e-6f, xr[k - 5], d);
        ws[WS_EDX + g] = EXP2F(-d * LOG2E_C);      // exp(-d), positive

        // weighted partials for the linear term (k=127 pad contributes 0)
        const int kc = (k < 127) ? k + 1 : 127;
        const float w = (k < 127) ? (1.f - xr[kc]) : 0.f;
        float c0 = w * d;
        float t0 = w * theta[kc];
        float t1 = w * theta[DX + kc];
        #pragma unroll
        for (int off = 32; off > 0; off >>= 1) {
            c0 += __shfl_xor(c0, off, 64);
            t0 += __shfl_xor(t0, off, 64);
            t1 += __shfl_xor(t1, off, 64);
        }
        if ((tid & 63) == 0) {
            rbuf[tid >> 6][0] = c0; rbuf[tid >> 6][1] = t0; rbuf[tid >> 6][2] = t1;
        }
        __syncthreads();
        if (tid == 0) {
            float a0 = 0.f, a1 = 0.f, a2 = 0.f;
            #pragma unroll
            for (int wv = 0; wv < 8; ++wv) { a0 += rbuf[wv][0]; a1 += rbuf[wv][1]; a2 += rbuf[wv][2]; }
            ws[WS_C0P + bid] = a0; ws[WS_T0P + bid] = a1; ws[WS_T1P + bid] = a2;
        }

        // second item: eu region upper half, t = gtid + 65536
        const int t = gtid + 65536;                // [65536, 131072)
        const int jd = t >> 7, kk = t & 127;
        const int kc2 = (kk < 127) ? (kk + 1) : 127;
        const float th0 = theta[kc2] * LOG2E_C;
        const float th1 = theta[DX + kc2] * LOG2E_C;
        ws[WS_EU + t] = EXP2F(-(z[jd * 2] * th0 + z[jd * 2 + 1] * th1));
    } else {                                       // eu region lower half
        const int t = gtid - 65536;                // [0, 65536)
        const int jd = t >> 7, kk = t & 127;
        const int kc2 = (kk < 127) ? (kk + 1) : 127;
        const float th0 = theta[kc2] * LOG2E_C;
        const float th1 = theta[DX + kc2] * LOG2E_C;
        ws[WS_EU + t] = EXP2F(-(z[jd * 2] * th0 + z[jd * 2 + 1] * th1));

        if (bid == 255) {                          // S0 = sum_i x[i,0]
            float s0 = x[tid * DX];                // 512 threads = 512 rows
            #pragma unroll
            for (int off = 32; off > 0; off >>= 1) s0 += __shfl_xor(s0, off, 64);
            if ((tid & 63) == 0) sbuf[tid >> 6] = s0;
            __syncthreads();
            if (tid == 0) {
                float a = 0.f;
                #pragma unroll
                for (int wv = 0; wv < 8; ++wv) a += sbuf[wv];
                ws[WS_S0] = a;
            }
        }
    }

    cg::this_grid().sync();

    // ================= phase 2: den-only product over 4 tiles/block ===========
    const int sub  = tid >> 8;                 // 0..1 (two 256-thread sub-blocks)
    const int stid = tid & 255;
    const int ke   = stid & 127;
    const int half = stid >> 7;
    const bool valid = (ke < 127);

    #pragma unroll
    for (int r = 0; r < 2; ++r) {
        const int t_idx = bid * 4 + sub * 2 + r;   // 0..1023
        const int jt = t_idx >> 4;                 // 0..63
        const int c  = t_idx & 15;                 // 0..15
        const int j0 = jt * NQ;

        const float* eub = ws + WS_EU + j0 * 256 + ke;
        v2f eu[NQ];
        #pragma unroll
        for (int q = 0; q < NQ; ++q) {             // {dz0, dz1} of j0+q
            eu[q].x = eub[q * 256];
            eu[q].y = eub[q * 256 + 128];
        }

        const float* ep = ws + WS_EDX + (c * 32 + half * 16) * 128 + ke;
        v2f den[NQ];
        int accX[NQ], accY[NQ];
        #pragma unroll
        for (int q = 0; q < NQ; ++q) { den[q] = splat2(1.f); accX[q] = 0; accY[q] = 0; }

        // 4 quads of 4 rows: prod (1 + ed_r*eu) = deg-4 poly in eu (Horner),
        // coefficients shared across all 16 streams. Strip every 8 rows.
        #pragma unroll
        for (int qd = 0; qd < 4; ++qd) {
            const float e0 = ep[(qd * 4 + 0) * 128];
            const float e1 = ep[(qd * 4 + 1) * 128];
            const float e2 = ep[(qd * 4 + 2) * 128];
            const float e3 = ep[(qd * 4 + 3) * 128];
            const float A1 = e0 * e1, B1 = e0 + e1;
            const float A2 = e2 * e3, B2 = e2 + e3;
            const float d4 = A1 * A2;
            const float d3 = __builtin_fmaf(B1, A2, A1 * B2);
            const float d2 = __builtin_fmaf(B1, B2, A1 + A2);
            const float d1 = B1 + B2;
            const v2f v4 = splat2(d4), v3 = splat2(d3), v2 = splat2(d2), v1 = splat2(d1);
            #pragma unroll
            for (int q = 0; q < NQ; ++q) {
                v2f t = v4 * eu[q] + v3;
                t = t * eu[q] + v2;
                t = t * eu[q] + v1;
                t = t * eu[q] + splat2(1.f);
                den[q] *= t;
            }
            if (qd & 1) {
                #pragma unroll
                for (int q = 0; q < NQ; ++q) {
                    den[q].x = strip_add(den[q].x, accX[q]);
                    den[q].y = strip_add(den[q].y, accY[q]);
                }
            }
        }

        // per-thread finalize: log2(den) = (acc - 254) + poly(m); reduce
        #pragma unroll
        for (int q = 0; q < NQ; ++q) {
            float vx = valid ? ((float)(accX[q] - 254) + log2s(den[q].x)) : 0.f;
            float vy = valid ? ((float)(accY[q] - 254) + log2s(den[q].y)) : 0.f;
            #pragma unroll
            for (int off = 32; off > 0; off >>= 1) {
                vx += __shfl_xor(vx, off, 64);
                vy += __shfl_xor(vy, off, 64);
            }
            if ((stid & 63) == 0) {
                red[sub][stid >> 6][2 * q] = vx;
                red[sub][stid >> 6][2 * q + 1] = vy;
            }
        }
        __syncthreads();
        if (stid < 16) {
            const float t = red[sub][0][stid] + red[sub][1][stid]
                          + red[sub][2][stid] + red[sub][3][stid];
            ws[WS_PART + (jt * 16 + stid) * 16 + c] = t;
        }
        __syncthreads();                           // red reused next iteration
    }

    cg::this_grid().sync();

    // ================= phase 3: finalize 1024 outputs on blocks 0-1 ===========
    if (bid < 2) {
        // reduce the 128 C0/T0/T1 partials (waves 0 and 1 cover slots 0-63, 64-127)
        float c0 = ws[WS_C0P + (tid & 127)];
        float t0 = ws[WS_T0P + (tid & 127)];
        float t1 = ws[WS_T1P + (tid & 127)];
        #pragma unroll
        for (int off = 32; off > 0; off >>= 1) {
            c0 += __shfl_xor(c0, off, 64);
            t0 += __shfl_xor(t0, off, 64);
            t1 += __shfl_xor(t1, off, 64);
        }
        if ((tid & 63) == 0) {
            fbuf[tid >> 6][0] = c0; fbuf[tid >> 6][1] = t0; fbuf[tid >> 6][2] = t1;
        }
        __syncthreads();
        const float C0 = fbuf[0][0] + fbuf[1][0];
        const float T0 = fbuf[0][1] + fbuf[1][1];
        const float T1 = fbuf[0][2] + fbuf[1][2];

        const int gid = bid * 512 + tid;           // 0..1023
        const int j = gid >> 1, dz = gid & 1;
        const int jt = j >> 3, o = (j & 7) * 2 + dz;
        const float z0 = z[j * 4 + dz * 2];
        const float z1 = z[j * 4 + dz * 2 + 1];

        float sp = 0.f;                            // sum of log2(1+e) partials
        #pragma unroll
        for (int cc = 0; cc < 16; ++cc)
            sp += ws[WS_PART + (jt * 16 + o) * 16 + cc];

        // lp = logpdf(z0,1e-3) + logpdf(z1,exp(z0/4)); log(exp(z0/4)) == z0/4
        const float u1 = z0 * 1000.f;
        const float e4 = __expf(-z0 * 0.25f);
        const float u2 = z1 * e4;
        const float lp = -0.5f * u1 * u1 + 6.9077552790f
                       - 0.5f * u2 * u2 - z0 * 0.25f - LOG2PI_C;

        // lp0 (exact, clamped)
        const float S0  = ws[WS_S0];
        const float up0 = z0 * theta[0] + z1 * theta[DX];
        const float p0  = 1.f / (1.f + __expf(-up0));
        const float lp0 = __logf(p0 - CLAMP_C) * S0
                        + __logf(1.f - p0 + CLAMP_C) * ((float)N - S0);

        out[j * 2 + dz] = lp + lp0 - sp * LN2_C - (C0 + z0 * T0 + z1 * T1);
    }
}

extern "C" void kernel_launch(void* const* d_in, const int* in_sizes, int n_in,
                              void* d_out, int out_size, void* d_ws, size_t ws_size,
                              hipStream_t stream) {
    const float* z     = (const float*)d_in[0];   // (512, 2, 2)
    const float* x     = (const float*)d_in[1];   // (512, 128)
    const float* theta = (const float*)d_in[2];   // (2, 128)
    float* ws  = (float*)d_ws;
    float* out = (float*)d_out;                   // (512, 2) float32

    void* args[] = {(void*)&z, (void*)&x, (void*)&theta, (void*)&ws, (void*)&out};
    hipLaunchCooperativeKernel((const void*)fused_kernel, dim3(256), dim3(512),
                               args, 0, stream);
}

// Round 10
// 17.270 us; speedup vs baseline: 4.8763x; 4.8763x over previous
//
#include <hip/hip_runtime.h>

typedef float v2f __attribute__((ext_vector_type(2)));

#define N 512
#define P 2
#define DX 128
#define CLAMP_C 1e-4f
#define LOG2E_C 1.4426950408889634f
#define LN2_C 0.6931471805599453f
#define LOG2PI_C 1.8378770664093453f

#define NQ 8                 // j-values per tile (16 output streams)

// ws float offsets
#define WS_EDX    0          // 65536: exp(-d[i,k]), [i][k] (k=127 pad, masked)
#define WS_EU     65536      // 131072: exp(-u[jd,k]), jd=j*2+dz
#define WS_C0P    196608     // 256: per-block partial of sum (1-x~)*d
#define WS_T0P    196864     // 256: partial of sum (1-x~)*theta0[k+1]
#define WS_T1P    197120     // 256: partial of sum (1-x~)*theta1[k+1]

#define EXP2F(v) __builtin_amdgcn_exp2f(v)

__device__ __forceinline__ v2f splat2(float a) { v2f r; r.x = a; r.y = a; return r; }

// log2(m) for m in [1,2): deg-5 Taylor @1.5, |err| <= ~4.6e-4 (budget ~1e5)
__device__ __forceinline__ float log2s(float m) {
    const float t = m - 1.5f;
    float p = t * 0.03799691f + -0.07124420f;
    p = p * t + 0.14248840f;
    p = p * t + -0.32059890f;
    p = p * t + 0.96179669f;
    p = p * t + 0.58496250f;
    return p;
}

// strip exponent into integer accumulator, renormalize mantissa to [1,2)
__device__ __forceinline__ float strip_add(float v, int& acc) {
    const unsigned b = __float_as_uint(v);
    acc += (int)(b >> 23);                         // biased; bias removed at end
    return __uint_as_float((b & 0x007fffffu) | 0x3f800000u);
}

// K1: edx table + eu table + C0/T0/T1 block-partials + zero out
__global__ __launch_bounds__(256)
void prep_kernel(const float* __restrict__ z, const float* __restrict__ x,
                 const float* __restrict__ theta, float* __restrict__ ws,
                 float* __restrict__ out) {
    const int tid = threadIdx.x;
    const int gid = blockIdx.x * 256 + tid;

    if (blockIdx.x < 256) {                        // edx region: gid < 65536
        const int i = gid >> 7, k = gid & 127;
        const float* xr = x + i * DX;
        // d[i,k] = sum_m 0.1^(m+1) x[i,k-m]; taps < 1e-7 dropped
        float d = 0.1f * xr[k];
        if (k >= 1) d = __builtin_fmaf(1e-2f, xr[k - 1], d);
        if (k >= 2) d = __builtin_fmaf(1e-3f, xr[k - 2], d);
        if (k >= 3) d = __builtin_fmaf(1e-4f, xr[k - 3], d);
        if (k >= 4) d = __builtin_fmaf(1e-5f, xr[k - 4], d);
        if (k >= 5) d = __builtin_fmaf(1e-6f, xr[k - 5], d);
        ws[WS_EDX + gid] = EXP2F(-d * LOG2E_C);    // exp(-d), positive

        // weighted partials for the linear term (k=127 pad contributes 0)
        const int kc = (k < 127) ? k + 1 : 127;
        const float w = (k < 127) ? (1.f - xr[kc]) : 0.f;
        float c0 = w * d;
        float t0 = w * theta[kc];
        float t1 = w * theta[DX + kc];
        #pragma unroll
        for (int off = 32; off > 0; off >>= 1) {
            c0 += __shfl_xor(c0, off, 64);
            t0 += __shfl_xor(t0, off, 64);
            t1 += __shfl_xor(t1, off, 64);
        }
        __shared__ float rbuf[4][3];
        if ((tid & 63) == 0) {
            rbuf[tid >> 6][0] = c0; rbuf[tid >> 6][1] = t0; rbuf[tid >> 6][2] = t1;
        }
        __syncthreads();
        if (tid == 0) {
            ws[WS_C0P + blockIdx.x] = rbuf[0][0] + rbuf[1][0] + rbuf[2][0] + rbuf[3][0];
            ws[WS_T0P + blockIdx.x] = rbuf[0][1] + rbuf[1][1] + rbuf[2][1] + rbuf[3][1];
            ws[WS_T1P + blockIdx.x] = rbuf[0][2] + rbuf[1][2] + rbuf[2][2] + rbuf[3][2];
        }
    } else {                                       // eu region
        const int t = gid - 65536;                 // [0, 131072)
        const int jd = t >> 7, k = t & 127;
        const int kc = (k < 127) ? (k + 1) : 127;  // pad clamped (masked later)
        const float th0 = theta[kc] * LOG2E_C;
        const float th1 = theta[DX + kc] * LOG2E_C;
        ws[WS_EU + t] = EXP2F(-(z[jd * 2] * th0 + z[jd * 2 + 1] * th1));

        if (blockIdx.x == 256) {                   // zero output accumulator
            ((float4*)out)[tid] = make_float4(0.f, 0.f, 0.f, 0.f);
        }
    }
}

// K2: 1024 chunk blocks (den-product, atomicAdd partial) + 1 const block
__global__ __launch_bounds__(256, 4)
void main_kernel(const float* __restrict__ z, const float* __restrict__ x,
                 const float* __restrict__ theta, float* __restrict__ ws,
                 float* __restrict__ out) {
    const int tid = threadIdx.x;

    if (blockIdx.x == 1024) {
        // ---- const block: S0, C0/T0/T1, lp, lp0, linear const -> atomicAdd ----
        float s0 = x[tid * DX] + x[(tid + 256) * DX];
        float c0 = ws[WS_C0P + tid];
        float t0 = ws[WS_T0P + tid];
        float t1 = ws[WS_T1P + tid];
        #pragma unroll
        for (int off = 32; off > 0; off >>= 1) {
            s0 += __shfl_xor(s0, off, 64);
            c0 += __shfl_xor(c0, off, 64);
            t0 += __shfl_xor(t0, off, 64);
            t1 += __shfl_xor(t1, off, 64);
        }
        __shared__ float cb[4][4];
        if ((tid & 63) == 0) {
            cb[tid >> 6][0] = s0; cb[tid >> 6][1] = c0;
            cb[tid >> 6][2] = t0; cb[tid >> 6][3] = t1;
        }
        __syncthreads();
        const float S0 = cb[0][0] + cb[1][0] + cb[2][0] + cb[3][0];
        const float C0 = cb[0][1] + cb[1][1] + cb[2][1] + cb[3][1];
        const float T0 = cb[0][2] + cb[1][2] + cb[2][2] + cb[3][2];
        const float T1 = cb[0][3] + cb[1][3] + cb[2][3] + cb[3][3];

        #pragma unroll
        for (int r = 0; r < 4; ++r) {
            const int gid = r * 256 + tid;         // 0..1023
            const int j = gid >> 1, dz = gid & 1;
            const float z0 = z[j * 4 + dz * 2];
            const float z1 = z[j * 4 + dz * 2 + 1];

            // lp = logpdf(z0,1e-3) + logpdf(z1,exp(z0/4)); log(exp(z0/4)) == z0/4
            const float u1 = z0 * 1000.f;
            const float e4 = __expf(-z0 * 0.25f);
            const float u2 = z1 * e4;
            const float lp = -0.5f * u1 * u1 + 6.9077552790f
                           - 0.5f * u2 * u2 - z0 * 0.25f - LOG2PI_C;

            // lp0 (exact, clamped)
            const float up0 = z0 * theta[0] + z1 * theta[DX];
            const float p0  = 1.f / (1.f + __expf(-up0));
            const float lp0 = __logf(p0 - CLAMP_C) * S0
                            + __logf(1.f - p0 + CLAMP_C) * ((float)N - S0);

            atomicAdd(&out[gid], lp + lp0 - (C0 + z0 * T0 + z1 * T1));
        }
        return;
    }

    // ---- chunk block: den-only product via quad-grouped Horner ----
    const int jt = blockIdx.x >> 4;            // 0..63
    const int c  = blockIdx.x & 15;            // 0..15
    const int j0 = jt * NQ;
    const int ke   = tid & 127;
    const int half = tid >> 7;
    const bool valid = (ke < 127);

    const float* eub = ws + WS_EU + j0 * 256 + ke;
    v2f eu[NQ];
    #pragma unroll
    for (int q = 0; q < NQ; ++q) {             // {dz0, dz1} of j0+q
        eu[q].x = eub[q * 256];
        eu[q].y = eub[q * 256 + 128];
    }

    const float* ep = ws + WS_EDX + (c * 32 + half * 16) * 128 + ke;
    v2f den[NQ];
    int accX[NQ], accY[NQ];
    #pragma unroll
    for (int q = 0; q < NQ; ++q) { den[q] = splat2(1.f); accX[q] = 0; accY[q] = 0; }

    // 4 quads of 4 rows: prod (1 + ed_r*eu) = deg-4 poly in eu (Horner),
    // coefficients shared across all 16 streams. Strip every 8 rows
    // (e < ~3e3 by reference finiteness -> product <= ~1e28 < f32 max).
    #pragma unroll
    for (int qd = 0; qd < 4; ++qd) {
        const float e0 = ep[(qd * 4 + 0) * 128];
        const float e1 = ep[(qd * 4 + 1) * 128];
        const float e2 = ep[(qd * 4 + 2) * 128];
        const float e3 = ep[(qd * 4 + 3) * 128];
        const float A1 = e0 * e1, B1 = e0 + e1;
        const float A2 = e2 * e3, B2 = e2 + e3;
        const float d4 = A1 * A2;
        const float d3 = __builtin_fmaf(B1, A2, A1 * B2);
        const float d2 = __builtin_fmaf(B1, B2, A1 + A2);
        const float d1 = B1 + B2;
        const v2f v4 = splat2(d4), v3 = splat2(d3), v2 = splat2(d2), v1 = splat2(d1);
        #pragma unroll
        for (int q = 0; q < NQ; ++q) {
            v2f t = v4 * eu[q] + v3;
            t = t * eu[q] + v2;
            t = t * eu[q] + v1;
            t = t * eu[q] + splat2(1.f);
            den[q] *= t;
        }
        if (qd & 1) {
            #pragma unroll
            for (int q = 0; q < NQ; ++q) {
                den[q].x = strip_add(den[q].x, accX[q]);
                den[q].y = strip_add(den[q].y, accY[q]);
            }
        }
    }

    // per-thread finalize: log2(den) = (acc - 254) + poly(m); reduce; atomicAdd
    __shared__ float red[4][16];
    #pragma unroll
    for (int q = 0; q < NQ; ++q) {
        float vx = valid ? ((float)(accX[q] - 254) + log2s(den[q].x)) : 0.f;
        float vy = valid ? ((float)(accY[q] - 254) + log2s(den[q].y)) : 0.f;
        #pragma unroll
        for (int off = 32; off > 0; off >>= 1) {
            vx += __shfl_xor(vx, off, 64);
            vy += __shfl_xor(vy, off, 64);
        }
        if ((tid & 63) == 0) { red[tid >> 6][2 * q] = vx; red[tid >> 6][2 * q + 1] = vy; }
    }
    __syncthreads();
    if (tid < 16) {
        const float t = red[0][tid] + red[1][tid] + red[2][tid] + red[3][tid];
        atomicAdd(&out[(j0 + (tid >> 1)) * 2 + (tid & 1)], -t * LN2_C);
    }
}

extern "C" void kernel_launch(void* const* d_in, const int* in_sizes, int n_in,
                              void* d_out, int out_size, void* d_ws, size_t ws_size,
                              hipStream_t stream) {
    const float* z     = (const float*)d_in[0];   // (512, 2, 2)
    const float* x     = (const float*)d_in[1];   // (512, 128)
    const float* theta = (const float*)d_in[2];   // (2, 128)
    float* ws  = (float*)d_ws;
    float* out = (float*)d_out;                   // (512, 2) float32

    hipLaunchKernelGGL(prep_kernel, dim3(768),  dim3(256), 0, stream, z, x, theta, ws, out);
    hipLaunchKernelGGL(main_kernel, dim3(1025), dim3(256), 0, stream, z, x, theta, ws, out);
}

// Round 11
// 14.579 us; speedup vs baseline: 5.7765x; 1.1846x over previous
//
#include <hip/hip_runtime.h>

#define DX 128
#define CLAMP_C 1e-4f
#define LOG2PI_C 1.8378770664093453f

// ws float offsets
#define WS_D   0      // [16][128]: block-partial of D_k = sum_i d[i,k]
#define WS_E2  2048   // [16][128]: partial of E2_k = sum_i d^2
#define WS_W   4096   // [16][128]: partial of W_k = sum_i (1 - x[i,k+1])
#define WS_C0  6144   // [16]: partial of C0 = sum_{ik} (1-x~) d
#define WS_S0  6160   // [16]: partial of S0 = sum_i x[i,0]

// K1: input-only stats. 16 blocks x 32 rows; LDS-staged FIR.
__global__ __launch_bounds__(256)
void k1_stats(const float* __restrict__ x, float* __restrict__ ws) {
    __shared__ float xs[32 * 128];
    __shared__ float cm[3][128];
    __shared__ float cred[4];
    const int tid = threadIdx.x, b = blockIdx.x;

    const float4* xg4 = (const float4*)(x + b * 32 * DX);
    float4* xs4 = (float4*)xs;
    #pragma unroll
    for (int t = 0; t < 4; ++t) xs4[tid + 256 * t] = xg4[tid + 256 * t];
    __syncthreads();

    const int k = tid & 127, rg = tid >> 7;
    const float* base = xs + rg * 16 * 128;
    float Dp = 0.f, E2p = 0.f, Wp = 0.f, C0p = 0.f;
    #pragma unroll
    for (int r = 0; r < 16; ++r) {
        const float* row = base + r * 128 + k;
        // d[i,k] = sum_m 0.1^(m+1) x[i,k-m]; taps < 1e-7 dropped
        float d = 0.1f * row[0];
        if (k >= 1) d = __builtin_fmaf(1e-2f, row[-1], d);
        if (k >= 2) d = __builtin_fmaf(1e-3f, row[-2], d);
        if (k >= 3) d = __builtin_fmaf(1e-4f, row[-3], d);
        if (k >= 4) d = __builtin_fmaf(1e-5f, row[-4], d);
        if (k >= 5) d = __builtin_fmaf(1e-6f, row[-5], d);
        Dp += d;
        E2p = __builtin_fmaf(d, d, E2p);
        const float w = (k < 127) ? (1.f - row[1]) : 0.f;   // x~ = x[i,k+1]
        Wp += w;
        C0p = __builtin_fmaf(w, d, C0p);
    }
    if (rg == 1) { cm[0][k] = Dp; cm[1][k] = E2p; cm[2][k] = Wp; }
    __syncthreads();
    if (rg == 0) {
        ws[WS_D  + b * 128 + k] = Dp  + cm[0][k];
        ws[WS_E2 + b * 128 + k] = E2p + cm[1][k];
        ws[WS_W  + b * 128 + k] = Wp  + cm[2][k];
    }

    float c0 = C0p;
    #pragma unroll
    for (int off = 32; off > 0; off >>= 1) c0 += __shfl_xor(c0, off, 64);
    if ((tid & 63) == 0) cred[tid >> 6] = c0;
    __syncthreads();
    if (tid < 64) {
        float s = (tid < 32) ? xs[tid * 128] : 0.f;          // x[row, 0]
        #pragma unroll
        for (int off = 32; off > 0; off >>= 1) s += __shfl_xor(s, off, 64);
        if (tid == 0) {
            ws[WS_C0 + b] = cred[0] + cred[1] + cred[2] + cred[3];
            ws[WS_S0 + b] = s;
        }
    }
}

// K2: per-output closed form. 256 blocks; block = j-pair (4 outputs).
__global__ __launch_bounds__(256)
void k2_out(const float* __restrict__ z, const float* __restrict__ theta,
            const float* __restrict__ ws, float* __restrict__ out) {
    const int tid = threadIdx.x;
    const int k = tid & 127;
    const int hf = tid >> 7;                   // half -> which j
    const int j = blockIdx.x * 2 + hf;
    const bool valid = (k < 127);
    const int kc = valid ? (k + 1) : 127;

    float D = 0.f, E2 = 0.f, W = 0.f;
    #pragma unroll
    for (int b = 0; b < 16; ++b) {
        D  += ws[WS_D  + b * 128 + k];
        E2 += ws[WS_E2 + b * 128 + k];
        W  += ws[WS_W  + b * 128 + k];
    }
    const float th0 = theta[kc];
    const float th1 = theta[DX + kc];

    float Sa = 0.f, Sb = 0.f, T0s = 0.f, T1s = 0.f;
    if (valid) {
        {   // dz = 0
            const float u  = z[j * 4 + 0] * th0 + z[j * 4 + 1] * th1;
            const float EU = __expf(-u);
            const float t  = 1.f + EU;
            const float r  = __builtin_amdgcn_rcpf(t);       // 1 - sigma
            const float lt = __logf(t);                      // softplus(-u)
            const float sg = EU * r;                         // sigma(-u)
            Sa = 512.f * lt;
            Sa = __builtin_fmaf(-sg, D, Sa);
            Sa = __builtin_fmaf(0.5f * sg * r, E2, Sa);      // + 1/2 sg(1-sg) E2
        }
        {   // dz = 1
            const float u  = z[j * 4 + 2] * th0 + z[j * 4 + 3] * th1;
            const float EU = __expf(-u);
            const float t  = 1.f + EU;
            const float r  = __builtin_amdgcn_rcpf(t);
            const float lt = __logf(t);
            const float sg = EU * r;
            Sb = 512.f * lt;
            Sb = __builtin_fmaf(-sg, D, Sb);
            Sb = __builtin_fmaf(0.5f * sg * r, E2, Sb);
        }
        T0s = th0 * W;
        T1s = th1 * W;
    }

    #pragma unroll
    for (int off = 32; off > 0; off >>= 1) {
        Sa  += __shfl_xor(Sa, off, 64);
        Sb  += __shfl_xor(Sb, off, 64);
        T0s += __shfl_xor(T0s, off, 64);
        T1s += __shfl_xor(T1s, off, 64);
    }
    __shared__ float red[4][4];
    const int wv = tid >> 6;
    if ((tid & 63) == 0) {
        red[wv][0] = Sa; red[wv][1] = Sb; red[wv][2] = T0s; red[wv][3] = T1s;
    }
    __syncthreads();
    if ((tid & 127) == 0) {                    // one finisher per half
        const int w0 = hf * 2;
        const float Sd[2] = { red[w0][0] + red[w0 + 1][0],
                              red[w0][1] + red[w0 + 1][1] };
        const float T0 = red[w0][2] + red[w0 + 1][2];
        const float T1 = red[w0][3] + red[w0 + 1][3];
        float C0 = 0.f, S0 = 0.f;
        #pragma unroll
        for (int b = 0; b < 16; ++b) { C0 += ws[WS_C0 + b]; S0 += ws[WS_S0 + b]; }

        #pragma unroll
        for (int dz = 0; dz < 2; ++dz) {
            const float z0 = z[j * 4 + dz * 2];
            const float z1 = z[j * 4 + dz * 2 + 1];
            // lp = logpdf(z0,1e-3) + logpdf(z1,exp(z0/4)); log(exp(z0/4)) == z0/4
            const float u1 = z0 * 1000.f;
            const float e4 = __expf(-z0 * 0.25f);
            const float u2 = z1 * e4;
            const float lp = -0.5f * u1 * u1 + 6.9077552790f
                           - 0.5f * u2 * u2 - z0 * 0.25f - LOG2PI_C;
            // lp0 (exact, clamped)
            const float up0 = z0 * theta[0] + z1 * theta[DX];
            const float p0  = 1.f / (1.f + __expf(-up0));
            const float lp0 = __logf(p0 - CLAMP_C) * S0
                            + __logf(1.f - p0 + CLAMP_C) * (512.f - S0);
            out[j * 2 + dz] = lp + lp0 - Sd[dz] - (C0 + z0 * T0 + z1 * T1);
        }
    }
}

extern "C" void kernel_launch(void* const* d_in, const int* in_sizes, int n_in,
                              void* d_out, int out_size, void* d_ws, size_t ws_size,
                              hipStream_t stream) {
    const float* z     = (const float*)d_in[0];   // (512, 2, 2)
    const float* x     = (const float*)d_in[1];   // (512, 128)
    const float* theta = (const float*)d_in[2];   // (2, 128)
    float* ws  = (float*)d_ws;
    float* out = (float*)d_out;                   // (512, 2) float32

    hipLaunchKernelGGL(k1_stats, dim3(16),  dim3(256), 0, stream, x, ws);
    hipLaunchKernelGGL(k2_out,   dim3(256), dim3(256), 0, stream, z, theta, ws, out);
}